// Round 11
// baseline (58.035 us; speedup 1.0000x reference)
//
#include <hip/hip_runtime.h>
#include <math.h>

#define DD 8
#define MM 7
#define MOO 9
#define NPTS 100
#define EPSF 1e-5f

#define THREADS 1024
#define ITERS 8           // uint4 loads per thread; THREADS*4*ITERS == 32768
#define CAP 256           // candidate buffer capacity per row
// Truncated-bf16 one-sided error bounds: f~ >= 0.992203*f, m^ >= 0.988326*f.
// Thread filter uses 0.9879 < 0.988326 (safe); rule filter uses exact f >= T.
#define THR_SLACK 0.9879f

// ---------------- pack: antecedents -> packed byte-offset word --------------
// lo 16 bits: byte offset into 8B-entry quad table 0 = (code & 4095) * 8
// hi 16 bits: byte offset into 8B-entry quad table 1 = (code >> 12) * 8 + 32768
// Entry index: lo_idx = (w&0xFFFF)>>3, hi_idx = w>>19 (includes +4096 base).
__global__ __launch_bounds__(256) void pack_kernel(const int* __restrict__ ant,
                                                   unsigned* __restrict__ g_off,
                                                   int R) {
    int r = blockIdx.x * 256 + threadIdx.x;
    if (r < R) {
        const int4* a = reinterpret_cast<const int4*>(ant) + (size_t)r * 2;
        int4 lo = a[0], hi = a[1];
        int v[8] = {lo.x, lo.y, lo.z, lo.w, hi.x, hi.y, hi.z, hi.w};
        unsigned code = 0u;
        #pragma unroll
        for (int i = 0; i < 8; ++i) {
            int c = v[i];
            c = (c < 0) ? 7 : (c > MM - 1 ? MM - 1 : c);   // -1 -> wildcard slot 7
            code |= (unsigned)c << (3 * i);
        }
        g_off[r] = ((code & 4095u) << 3) | ((((code >> 12) << 3) + 32768u) << 16);
    }
}

// ---------------- main kernel: 1024 threads per FOUR batch rows -------------
// R10 structure + phase-3 MLP fence: R6-R10 all ran at VGPR_Count 24-32 --
// the compiler sank every "preloaded" ds_read to its use, leaving ~2-4
// outstanding LDS ops and exposing ~120cyc latency per rule pair (both pipes
// ~28%). The empty-asm "+v" fence forces all 16 ds_read_b64 results of an
// 8-rule batch to be resident simultaneously -> 16 outstanding reads, one
// waitcnt per batch.
__global__ __launch_bounds__(THREADS, 8) void anfis4(
    const float* __restrict__ x,
    const unsigned* __restrict__ stream_off,   // packed words, original order
    const int* __restrict__ consequents,
    const float* __restrict__ in_centers,   // [D][M]
    const float* __restrict__ in_widths,    // [D][M]
    const float* __restrict__ out_centers,  // [MO]
    const float* __restrict__ out_widths,   // [MO]
    float* __restrict__ out)
{
    __shared__ uint2   quads[8192];      // 64 KB: 2 tables x 4096, bf16x4 rows
    __shared__ float   mu[4][64];        // [row][d*8+c], c==7 -> 1.0
    __shared__ float   pairs[4][256];    // 4 KB exact f32 pair products
    __shared__ float   s0s[MOO], s1s[MOO];
    __shared__ uint2   scratch8[1024];   // 8 KB: smaxpk (ph3-4) THEN cval/cidx (ph5-6)
    __shared__ float   sT[4];            // per-row threshold T (exact domain)
    __shared__ int     scnt[4];
    __shared__ float   wv[4][8];
    __shared__ int     wc[4][8];

    const int tid = threadIdx.x;
    const int b0  = blockIdx.x * 4;

    float* cvals = (float*)scratch8;            // [4][256]
    int*   cidx  = (int*)scratch8 + 1024;       // [4][256]

    // --- phase 0: membership tables (4 rows) + defuzz constants ---
    if (tid < 256) {
        int row = tid >> 6, d = (tid >> 3) & 7, c = tid & 7;
        float v = 1.0f;
        if (c < MM) {
            float z = (x[(b0 + row) * DD + d] - in_centers[d * MM + c]) / in_widths[d * MM + c];
            v = expf(-0.5f * z * z);
            v = fminf(v, 1.0f);
            v = fmaxf(v, EPSF);
        }
        mu[row][(d << 3) + c] = v;
    } else if (tid < 256 + MOO) {
        int mo = tid - 256;
        float oc = out_centers[mo], ow = out_widths[mo];
        float s0 = 0.0f, s1 = 0.0f;
        for (int p = 0; p < NPTS; ++p) {
            float u = (float)p * (1.0f / 99.0f);
            float z = (u - oc) / ow;
            float e = expf(-0.5f * z * z);
            s0 += e;
            s1 += u * e;
        }
        s0s[mo] = s0;
        s1s[mo] = s1;
    }
    if (tid >= 512 && tid < 516) scnt[tid - 512] = 0;
    __syncthreads();

    // --- phase 1: exact pair products, 4 rows (1024 entries, one each) ---
    {
        int row = tid >> 8, e = tid & 255;
        int p = e >> 6, q = e & 63;
        pairs[row][e] = mu[row][(2 * p) * 8 + (q & 7)] * mu[row][(2 * p + 1) * 8 + (q >> 3)];
    }
    __syncthreads();

    // --- phase 2: quad tables, truncated bf16 x 4 rows per 8B entry ---
    #pragma unroll
    for (int i = 0; i < 8; ++i) {
        int k = tid + i * THREADS;
        int t = k & 4095, h = k >> 12;       // h in {0,1}
        int ia = h * 128 + (t & 63), ib = h * 128 + 64 + ((t >> 6) & 63);
        float p0 = pairs[0][ia] * pairs[0][ib];
        float p1 = pairs[1][ia] * pairs[1][ib];
        float p2 = pairs[2][ia] * pairs[2][ib];
        float p3 = pairs[3][ia] * pairs[3][ib];
        unsigned lo01 = (__float_as_uint(p1) & 0xFFFF0000u) | (__float_as_uint(p0) >> 16);
        unsigned hi23 = (__float_as_uint(p3) & 0xFFFF0000u) | (__float_as_uint(p2) >> 16);
        quads[k] = make_uint2(lo01, hi23);
    }
    __syncthreads();

    // --- phase 3: scan all rules; 8-rule batches with forced-resident reads ---
    const uint4* pk4 = reinterpret_cast<const uint4*>(stream_off);
    float m0 = -1.0f, m1 = -1.0f, m2 = -1.0f, m3 = -1.0f;
    #pragma unroll
    for (int half = 0; half < 4; ++half) {
        uint4 cA = pk4[(2 * half) * THREADS + tid];
        uint4 cB = pk4[(2 * half + 1) * THREADS + tid];
        unsigned w[8] = {cA.x, cA.y, cA.z, cA.w, cB.x, cB.y, cB.z, cB.w};
        uint2 lo[8], hi[8];
        #pragma unroll
        for (int s = 0; s < 8; ++s) {
            lo[s] = quads[(w[s] & 0xFFFFu) >> 3];
            hi[s] = quads[w[s] >> 19];
        }
        // Liveness fence: all 16 ds_read_b64 results must be in VGPRs here.
        // Prevents the compiler sinking loads to uses (VGPR=32 in R6-R10).
        asm volatile("" :
            "+v"(lo[0].x), "+v"(lo[0].y), "+v"(lo[1].x), "+v"(lo[1].y),
            "+v"(lo[2].x), "+v"(lo[2].y), "+v"(lo[3].x), "+v"(lo[3].y),
            "+v"(lo[4].x), "+v"(lo[4].y), "+v"(lo[5].x), "+v"(lo[5].y),
            "+v"(lo[6].x), "+v"(lo[6].y), "+v"(lo[7].x), "+v"(lo[7].y),
            "+v"(hi[0].x), "+v"(hi[0].y), "+v"(hi[1].x), "+v"(hi[1].y),
            "+v"(hi[2].x), "+v"(hi[2].y), "+v"(hi[3].x), "+v"(hi[3].y),
            "+v"(hi[4].x), "+v"(hi[4].y), "+v"(hi[5].x), "+v"(hi[5].y),
            "+v"(hi[6].x), "+v"(hi[6].y), "+v"(hi[7].x), "+v"(hi[7].y));
        #pragma unroll
        for (int s = 0; s < 8; ++s) {
            float a0 = __uint_as_float(lo[s].x << 16);
            float a1 = __uint_as_float(lo[s].x & 0xFFFF0000u);
            float a2 = __uint_as_float(lo[s].y << 16);
            float a3 = __uint_as_float(lo[s].y & 0xFFFF0000u);
            float b0 = __uint_as_float(hi[s].x << 16);
            float b1 = __uint_as_float(hi[s].x & 0xFFFF0000u);
            float b2 = __uint_as_float(hi[s].y << 16);
            float b3 = __uint_as_float(hi[s].y & 0xFFFF0000u);
            m0 = fmaxf(m0, a0 * b0);
            m1 = fmaxf(m1, a1 * b1);
            m2 = fmaxf(m2, a2 * b2);
            m3 = fmaxf(m3, a3 * b3);
        }
    }
    // pack thread maxes (truncate to bf16, one-sided) into aliased buffer
    {
        unsigned pkx = (__float_as_uint(m1) & 0xFFFF0000u) | (__float_as_uint(m0) >> 16);
        unsigned pky = (__float_as_uint(m3) & 0xFFFF0000u) | (__float_as_uint(m2) >> 16);
        scratch8[tid] = make_uint2(pkx, pky);
    }
    __syncthreads();

    // --- phase 4: wave w extracts 8th-largest packed thread-max of row w ---
    if (tid < 256) {
        int w = tid >> 6, lane = tid & 63;
        float m[16];
        #pragma unroll
        for (int k = 0; k < 16; ++k) {
            uint2 e = scratch8[lane + 64 * k];
            unsigned sel = (w & 2) ? e.y : e.x;
            unsigned bits = (w & 1) ? (sel & 0xFFFF0000u) : (sel << 16);
            m[k] = __uint_as_float(bits);
        }
        float thr = -1.0f;
        #pragma unroll
        for (int round = 0; round < 8; ++round) {
            float lm = m[0];
            #pragma unroll
            for (int k = 1; k < 16; ++k) lm = fmaxf(lm, m[k]);
            float wm = lm;
            #pragma unroll
            for (int off = 32; off >= 1; off >>= 1)
                wm = fmaxf(wm, __shfl_xor(wm, off, 64));
            unsigned long long bal = __ballot(lm == wm);
            int first = (int)__ffsll(bal) - 1;
            if (lane == first) {                // remove exactly one instance
                bool done = false;
                #pragma unroll
                for (int k = 0; k < 16; ++k) {
                    bool rm = (!done) && (m[k] == wm);
                    m[k] = rm ? -2.0f : m[k];
                    done = done || rm;
                }
            }
            thr = wm;
        }
        if (lane == 0) sT[w] = thr;
    }
    __syncthreads();   // also: scratch8 reads done -> safe to reuse as cval/cidx

    // --- phase 5: qualifying threads recompute EXACT f from pairs, push ---
    {
        float mym[4] = {m0, m1, m2, m3};
        #pragma unroll
        for (int row = 0; row < 4; ++row) {
            float T = sT[row];
            if (mym[row] >= THR_SLACK * T) {       // ~30-80 threads per row
                const float* P = pairs[row];
                for (int j = 0; j < ITERS; ++j) {
                    uint4 cd = pk4[j * THREADS + tid];
                    unsigned cods[4] = {cd.x, cd.y, cd.z, cd.w};
                    #pragma unroll
                    for (int s = 0; s < 4; ++s) {
                        unsigned w = cods[s];
                        unsigned lo12 = (w & 0xFFFFu) >> 3;
                        unsigned hi12 = (w >> 19) - 4096u;
                        float f = (P[lo12 & 63u] * P[64 + (lo12 >> 6)])
                                * (P[128 + (hi12 & 63u)] * P[192 + (hi12 >> 6)]);
                        if (f >= T) {
                            int flat = (j * THREADS + tid) * 4 + s;
                            int pos = atomicAdd(&scnt[row], 1);
                            if (pos < CAP) {
                                cvals[row * CAP + pos] = f;
                                cidx[row * CAP + pos]  = flat;
                            }
                        }
                    }
                }
            }
        }
    }
    __syncthreads();

    // --- phase 6: exact rank selection per row (val desc, orig idx asc) ---
    if (tid < 256) {
        int row = tid >> 6, lane = tid & 63;
        int n = scnt[row] < CAP ? scnt[row] : CAP;
        for (int c = lane; c < n; c += 64) {
            float v  = cvals[row * CAP + c];
            int   id = cidx[row * CAP + c];
            int rk = 0;
            for (int mI = 0; mI < n; ++mI) {
                float vm = cvals[row * CAP + mI];
                int   im = cidx[row * CAP + mI];
                rk += ((vm > v) || (vm == v && im < id)) ? 1 : 0;
            }
            if (rk < 8) {
                wv[row][rk] = v;
                wc[row][rk] = consequents[id];
            }
        }
    }
    __syncthreads();

    // --- phase 7: defuzzify (one thread per row) ---
    if (tid < 4) {
        int row = tid;
        float num = 0.0f, den = 0.0f;
        #pragma unroll
        for (int k = 0; k < 8; ++k) {
            num += wv[row][k] * s1s[wc[row][k]];
            den += wv[row][k] * s0s[wc[row][k]];
        }
        out[b0 + row] = num / (den + EPSF);
    }
}

// ---------------- generic fallback (round-1 kernel, inline pack) ------------
__global__ __launch_bounds__(256) void anfis_kernel(
    const float* __restrict__ x,
    const int* __restrict__ ant,
    const int* __restrict__ consequents,
    const float* __restrict__ in_centers,
    const float* __restrict__ in_widths,
    const float* __restrict__ out_centers,
    const float* __restrict__ out_widths,
    float* __restrict__ out,
    int R)
{
    __shared__ float mu[64];
    __shared__ float pairs[256];
    __shared__ float s0s[MOO], s1s[MOO];
    __shared__ float svals[256][9];
    __shared__ int   sidx[256][9];

    const int tid = threadIdx.x;
    const int b   = blockIdx.x;

    if (tid < 64) {
        int d = tid >> 3, c = tid & 7;
        float v = 1.0f;
        if (c < MM) {
            float z = (x[b * DD + d] - in_centers[d * MM + c]) / in_widths[d * MM + c];
            v = expf(-0.5f * z * z);
            v = fminf(v, 1.0f);
            v = fmaxf(v, EPSF);
        }
        mu[tid] = v;
    } else if (tid < 64 + MOO) {
        int mo = tid - 64;
        float oc = out_centers[mo], ow = out_widths[mo];
        float s0 = 0.0f, s1 = 0.0f;
        for (int p = 0; p < NPTS; ++p) {
            float u = (float)p * (1.0f / 99.0f);
            float z = (u - oc) / ow;
            float e = expf(-0.5f * z * z);
            s0 += e;
            s1 += u * e;
        }
        s0s[mo] = s0;
        s1s[mo] = s1;
    }
    __syncthreads();

    {
        int p = tid >> 6, q = tid & 63;
        pairs[tid] = mu[(2 * p) * 8 + (q & 7)] * mu[(2 * p + 1) * 8 + (q >> 3)];
    }
    __syncthreads();

    float vals[8];
    int   idxs[8];
    #pragma unroll
    for (int k = 0; k < 8; ++k) { vals[k] = -1.0f; idxs[k] = 0x7fffffff; }

    for (int r = tid; r < R; r += 256) {
        const int4* a = reinterpret_cast<const int4*>(ant) + (size_t)r * 2;
        int4 lo = a[0], hi = a[1];
        int v[8] = {lo.x, lo.y, lo.z, lo.w, hi.x, hi.y, hi.z, hi.w};
        unsigned code = 0u;
        #pragma unroll
        for (int i = 0; i < 8; ++i) {
            int c = v[i];
            c = (c < 0) ? 7 : (c > MM - 1 ? MM - 1 : c);
            code |= (unsigned)c << (3 * i);
        }
        float f = pairs[code & 63]
                * pairs[64  + ((code >> 6)  & 63)]
                * pairs[128 + ((code >> 12) & 63)]
                * pairs[192 + ((code >> 18) & 63)];
        if (f > vals[7]) {
            float nv = f; int ni = r;
            #pragma unroll
            for (int k = 0; k < 8; ++k) {
                bool take = nv > vals[k];
                float cv = vals[k]; int ci = idxs[k];
                vals[k] = take ? nv : cv;
                idxs[k] = take ? ni : ci;
                nv = take ? cv : nv;
                ni = take ? ci : ni;
            }
        }
    }

    #pragma unroll
    for (int k = 0; k < 8; ++k) { svals[tid][k] = vals[k]; sidx[tid][k] = idxs[k]; }

    for (int off = 128; off >= 1; off >>= 1) {
        __syncthreads();
        if (tid < off) {
            float ov[8]; int oi[8];
            int pa = 0, pb = 0;
            #pragma unroll
            for (int k = 0; k < 8; ++k) {
                float va = svals[tid][pa];        int ia = sidx[tid][pa];
                float vb = svals[tid + off][pb];  int ib = sidx[tid + off][pb];
                bool ta = (va > vb) || ((va == vb) && (ia < ib));
                ov[k] = ta ? va : vb;
                oi[k] = ta ? ia : ib;
                pa += ta ? 1 : 0;
                pb += ta ? 0 : 1;
            }
            #pragma unroll
            for (int k = 0; k < 8; ++k) { svals[tid][k] = ov[k]; sidx[tid][k] = oi[k]; }
        }
    }
    __syncthreads();

    if (tid == 0) {
        float num = 0.0f, den = 0.0f;
        #pragma unroll
        for (int k = 0; k < 8; ++k) {
            float v = svals[0][k];
            int   c = consequents[sidx[0][k]];
            num += v * s1s[c];
            den += v * s0s[c];
        }
        out[b] = num / (den + EPSF);
    }
}

extern "C" void kernel_launch(void* const* d_in, const int* in_sizes, int n_in,
                              void* d_out, int out_size, void* d_ws, size_t ws_size,
                              hipStream_t stream) {
    const float* x      = (const float*)d_in[0];
    const int*   ant    = (const int*)d_in[1];
    const int*   cons   = (const int*)d_in[2];
    const float* in_c   = (const float*)d_in[3];
    const float* in_w   = (const float*)d_in[4];
    const float* out_c  = (const float*)d_in[5];
    const float* out_w  = (const float*)d_in[6];
    float*       out    = (float*)d_out;

    const int B = in_sizes[0] / DD;
    const int R = in_sizes[1] / DD;

    const bool shape_ok = (R == THREADS * 4 * ITERS) && (B % 4 == 0);
    const size_t need = (size_t)R * 4;    // packed words only

    if (shape_ok && d_ws && ws_size >= need) {
        unsigned* g_off = (unsigned*)d_ws;
        pack_kernel<<<(R + 255) / 256, 256, 0, stream>>>(ant, g_off, R);
        anfis4<<<B / 4, THREADS, 0, stream>>>(x, g_off, cons,
                                              in_c, in_w, out_c, out_w, out);
    } else {
        anfis_kernel<<<B, 256, 0, stream>>>(x, ant, cons, in_c, in_w,
                                            out_c, out_w, out, R);
    }
}

// Round 12
// 56.589 us; speedup vs baseline: 1.0256x; 1.0256x over previous
//
#include <hip/hip_runtime.h>
#include <math.h>

#define DD 8
#define MM 7
#define MOO 9
#define NPTS 100
#define EPSF 1e-5f

#define THREADS 1024
#define ITERS 8           // uint4 loads per thread; THREADS*4*ITERS == 32768
#define CAP 256           // candidate buffer capacity per row
#define NBLK 512          // B / 4
// Truncated-bf16 one-sided error bounds: f~ >= 0.992203*f, m^ >= 0.988326*f.
// Thread filter uses 0.9879 < 0.988326 (safe); rule filter uses exact f >= T.
#define THR_SLACK 0.9879f

// ---------------- pack: antecedents -> packed byte-offset word --------------
// lo 16 bits: byte offset into 8B-entry quad table 0 = (code & 4095) * 8
// hi 16 bits: byte offset into 8B-entry quad table 1 = (code >> 12) * 8 + 32768
__global__ __launch_bounds__(256) void pack_kernel(const int* __restrict__ ant,
                                                   unsigned* __restrict__ g_off,
                                                   int R) {
    int r = blockIdx.x * 256 + threadIdx.x;
    if (r < R) {
        const int4* a = reinterpret_cast<const int4*>(ant) + (size_t)r * 2;
        int4 lo = a[0], hi = a[1];
        int v[8] = {lo.x, lo.y, lo.z, lo.w, hi.x, hi.y, hi.z, hi.w};
        unsigned code = 0u;
        #pragma unroll
        for (int i = 0; i < 8; ++i) {
            int c = v[i];
            c = (c < 0) ? 7 : (c > MM - 1 ? MM - 1 : c);   // -1 -> wildcard slot 7
            code |= (unsigned)c << (3 * i);
        }
        g_off[r] = ((code & 4095u) << 3) | ((((code >> 12) << 3) + 32768u) << 16);
    }
}

// =================== KERNEL A: scan (phases 0-4 + bitmap) ===================
// Per block (4 batch rows): build tables, scan all rules (bf16x4 per
// ds_read_b64), extract per-row threshold T, write T + per-wave ballot of
// qualifying threads. NO divergent select phases -- this isolates the scan
// cost in rocprof (6 rounds of phase-3 rewrites were time-invariant; the
// split is the ablation that localizes the real term).
__global__ __launch_bounds__(THREADS, 8) void anfis_scan(
    const float* __restrict__ x,
    const unsigned* __restrict__ stream_off,
    const float* __restrict__ in_centers,   // [D][M]
    const float* __restrict__ in_widths,    // [D][M]
    float* __restrict__ g_thr,              // [NBLK*4]
    unsigned long long* __restrict__ g_bitmap)  // [NBLK*4*16]
{
    __shared__ uint2   quads[8192];      // 64 KB: 2 tables x 4096, bf16x4 rows
    __shared__ float   mu[4][64];
    __shared__ float   pairs[4][256];
    __shared__ uint2   smaxpk[1024];     // 8 KB packed thread maxes
    __shared__ float   sT[4];

    const int tid = threadIdx.x;
    const int b0  = blockIdx.x * 4;

    // --- phase 0: membership tables (4 rows) ---
    if (tid < 256) {
        int row = tid >> 6, d = (tid >> 3) & 7, c = tid & 7;
        float v = 1.0f;
        if (c < MM) {
            float z = (x[(b0 + row) * DD + d] - in_centers[d * MM + c]) / in_widths[d * MM + c];
            v = expf(-0.5f * z * z);
            v = fminf(v, 1.0f);
            v = fmaxf(v, EPSF);
        }
        mu[row][(d << 3) + c] = v;
    }
    __syncthreads();

    // --- phase 1: exact pair products ---
    {
        int row = tid >> 8, e = tid & 255;
        int p = e >> 6, q = e & 63;
        pairs[row][e] = mu[row][(2 * p) * 8 + (q & 7)] * mu[row][(2 * p + 1) * 8 + (q >> 3)];
    }
    __syncthreads();

    // --- phase 2: quad tables, truncated bf16 x 4 rows per 8B entry ---
    #pragma unroll
    for (int i = 0; i < 8; ++i) {
        int k = tid + i * THREADS;
        int t = k & 4095, h = k >> 12;
        int ia = h * 128 + (t & 63), ib = h * 128 + 64 + ((t >> 6) & 63);
        float p0 = pairs[0][ia] * pairs[0][ib];
        float p1 = pairs[1][ia] * pairs[1][ib];
        float p2 = pairs[2][ia] * pairs[2][ib];
        float p3 = pairs[3][ia] * pairs[3][ib];
        unsigned lo01 = (__float_as_uint(p1) & 0xFFFF0000u) | (__float_as_uint(p0) >> 16);
        unsigned hi23 = (__float_as_uint(p3) & 0xFFFF0000u) | (__float_as_uint(p2) >> 16);
        quads[k] = make_uint2(lo01, hi23);
    }
    __syncthreads();

    // --- phase 3: scan all rules, track per-thread maxes (4 rows) ---
    const uint4* pk4 = reinterpret_cast<const uint4*>(stream_off);
    float m0 = -1.0f, m1 = -1.0f, m2 = -1.0f, m3 = -1.0f;
    #pragma unroll
    for (int j = 0; j < ITERS; ++j) {
        uint4 cd = pk4[j * THREADS + tid];
        unsigned w[4] = {cd.x, cd.y, cd.z, cd.w};
        #pragma unroll
        for (int s = 0; s < 4; ++s) {
            uint2 eA = quads[(w[s] & 0xFFFFu) >> 3];
            uint2 eB = quads[w[s] >> 19];
            float a0 = __uint_as_float(eA.x << 16);
            float a1 = __uint_as_float(eA.x & 0xFFFF0000u);
            float a2 = __uint_as_float(eA.y << 16);
            float a3 = __uint_as_float(eA.y & 0xFFFF0000u);
            float b0 = __uint_as_float(eB.x << 16);
            float b1 = __uint_as_float(eB.x & 0xFFFF0000u);
            float b2 = __uint_as_float(eB.y << 16);
            float b3 = __uint_as_float(eB.y & 0xFFFF0000u);
            m0 = fmaxf(m0, a0 * b0);
            m1 = fmaxf(m1, a1 * b1);
            m2 = fmaxf(m2, a2 * b2);
            m3 = fmaxf(m3, a3 * b3);
        }
    }
    {
        unsigned pkx = (__float_as_uint(m1) & 0xFFFF0000u) | (__float_as_uint(m0) >> 16);
        unsigned pky = (__float_as_uint(m3) & 0xFFFF0000u) | (__float_as_uint(m2) >> 16);
        smaxpk[tid] = make_uint2(pkx, pky);
    }
    __syncthreads();

    // --- phase 4: wave w (w<4) extracts 8th-largest packed thread-max ---
    if (tid < 256) {
        int w = tid >> 6, lane = tid & 63;
        float m[16];
        #pragma unroll
        for (int k = 0; k < 16; ++k) {
            uint2 e = smaxpk[lane + 64 * k];
            unsigned sel = (w & 2) ? e.y : e.x;
            unsigned bits = (w & 1) ? (sel & 0xFFFF0000u) : (sel << 16);
            m[k] = __uint_as_float(bits);
        }
        float thr = -1.0f;
        #pragma unroll
        for (int round = 0; round < 8; ++round) {
            float lm = m[0];
            #pragma unroll
            for (int k = 1; k < 16; ++k) lm = fmaxf(lm, m[k]);
            float wm = lm;
            #pragma unroll
            for (int off = 32; off >= 1; off >>= 1)
                wm = fmaxf(wm, __shfl_xor(wm, off, 64));
            unsigned long long bal = __ballot(lm == wm);
            int first = (int)__ffsll(bal) - 1;
            if (lane == first) {
                bool done = false;
                #pragma unroll
                for (int k = 0; k < 16; ++k) {
                    bool rm = (!done) && (m[k] == wm);
                    m[k] = rm ? -2.0f : m[k];
                    done = done || rm;
                }
            }
            thr = wm;
        }
        if (lane == 0) sT[w] = thr;
    }
    __syncthreads();

    // --- emit: thresholds + per-wave qualify ballots ---
    {
        const int wid = tid >> 6, lane = tid & 63;
        float mym[4] = {m0, m1, m2, m3};
        #pragma unroll
        for (int row = 0; row < 4; ++row) {
            unsigned long long bal = __ballot(mym[row] >= THR_SLACK * sT[row]);
            if (lane == 0)
                g_bitmap[((size_t)blockIdx.x * 4 + row) * 16 + wid] = bal;
        }
        if (tid < 4) g_thr[blockIdx.x * 4 + tid] = sT[tid];
    }
}

// =================== KERNEL B: select (phases 5-7) ==========================
// Tiny LDS (~14KB). Rebuilds exact pairs, reads qualify bitmap; qualifying
// threads recompute their 32 rules EXACTLY and push f >= T; exact rank
// selection (val desc, original idx asc) -> bit-identical output.
__global__ __launch_bounds__(THREADS, 8) void anfis_select(
    const float* __restrict__ x,
    const unsigned* __restrict__ stream_off,
    const int* __restrict__ consequents,
    const float* __restrict__ in_centers,
    const float* __restrict__ in_widths,
    const float* __restrict__ out_centers,
    const float* __restrict__ out_widths,
    const float* __restrict__ g_thr,
    const unsigned long long* __restrict__ g_bitmap,
    float* __restrict__ out)
{
    __shared__ float mu[4][64];
    __shared__ float pairs[4][256];
    __shared__ float s0s[MOO], s1s[MOO];
    __shared__ float cvals[4][CAP];
    __shared__ int   cidx[4][CAP];
    __shared__ int   scnt[4];
    __shared__ float wv[4][8];
    __shared__ int   wc[4][8];

    const int tid = threadIdx.x;
    const int b0  = blockIdx.x * 4;

    // --- phase 0: membership + defuzz constants ---
    if (tid < 256) {
        int row = tid >> 6, d = (tid >> 3) & 7, c = tid & 7;
        float v = 1.0f;
        if (c < MM) {
            float z = (x[(b0 + row) * DD + d] - in_centers[d * MM + c]) / in_widths[d * MM + c];
            v = expf(-0.5f * z * z);
            v = fminf(v, 1.0f);
            v = fmaxf(v, EPSF);
        }
        mu[row][(d << 3) + c] = v;
    } else if (tid < 256 + MOO) {
        int mo = tid - 256;
        float oc = out_centers[mo], ow = out_widths[mo];
        float s0 = 0.0f, s1 = 0.0f;
        for (int p = 0; p < NPTS; ++p) {
            float u = (float)p * (1.0f / 99.0f);
            float z = (u - oc) / ow;
            float e = expf(-0.5f * z * z);
            s0 += e;
            s1 += u * e;
        }
        s0s[mo] = s0;
        s1s[mo] = s1;
    }
    if (tid >= 512 && tid < 516) scnt[tid - 512] = 0;
    __syncthreads();

    // --- phase 1: exact pair products ---
    {
        int row = tid >> 8, e = tid & 255;
        int p = e >> 6, q = e & 63;
        pairs[row][e] = mu[row][(2 * p) * 8 + (q & 7)] * mu[row][(2 * p + 1) * 8 + (q >> 3)];
    }
    __syncthreads();

    // --- phase 5: qualifying threads (from bitmap) recompute exactly ---
    const uint4* pk4 = reinterpret_cast<const uint4*>(stream_off);
    {
        const int wid = tid >> 6, lane = tid & 63;
        #pragma unroll
        for (int row = 0; row < 4; ++row) {
            unsigned long long bal = g_bitmap[((size_t)blockIdx.x * 4 + row) * 16 + wid];
            if ((bal >> lane) & 1ull) {
                const float T = g_thr[blockIdx.x * 4 + row];
                const float* P = pairs[row];
                for (int j = 0; j < ITERS; ++j) {
                    uint4 cd = pk4[j * THREADS + tid];
                    unsigned cods[4] = {cd.x, cd.y, cd.z, cd.w};
                    #pragma unroll
                    for (int s = 0; s < 4; ++s) {
                        unsigned w = cods[s];
                        unsigned lo12 = (w & 0xFFFFu) >> 3;
                        unsigned hi12 = (w >> 19) - 4096u;
                        float f = (P[lo12 & 63u] * P[64 + (lo12 >> 6)])
                                * (P[128 + (hi12 & 63u)] * P[192 + (hi12 >> 6)]);
                        if (f >= T) {
                            int flat = (j * THREADS + tid) * 4 + s;
                            int pos = atomicAdd(&scnt[row], 1);
                            if (pos < CAP) {
                                cvals[row][pos] = f;
                                cidx[row][pos]  = flat;
                            }
                        }
                    }
                }
            }
        }
    }
    __syncthreads();

    // --- phase 6: exact rank selection per row (val desc, orig idx asc) ---
    if (tid < 256) {
        int row = tid >> 6, lane = tid & 63;
        int n = scnt[row] < CAP ? scnt[row] : CAP;
        for (int c = lane; c < n; c += 64) {
            float v  = cvals[row][c];
            int   id = cidx[row][c];
            int rk = 0;
            for (int mI = 0; mI < n; ++mI) {
                float vm = cvals[row][mI];
                int   im = cidx[row][mI];
                rk += ((vm > v) || (vm == v && im < id)) ? 1 : 0;
            }
            if (rk < 8) {
                wv[row][rk] = v;
                wc[row][rk] = consequents[id];
            }
        }
    }
    __syncthreads();

    // --- phase 7: defuzzify ---
    if (tid < 4) {
        int row = tid;
        float num = 0.0f, den = 0.0f;
        #pragma unroll
        for (int k = 0; k < 8; ++k) {
            num += wv[row][k] * s1s[wc[row][k]];
            den += wv[row][k] * s0s[wc[row][k]];
        }
        out[b0 + row] = num / (den + EPSF);
    }
}

// ---------------- generic fallback (round-1 kernel, inline pack) ------------
__global__ __launch_bounds__(256) void anfis_kernel(
    const float* __restrict__ x,
    const int* __restrict__ ant,
    const int* __restrict__ consequents,
    const float* __restrict__ in_centers,
    const float* __restrict__ in_widths,
    const float* __restrict__ out_centers,
    const float* __restrict__ out_widths,
    float* __restrict__ out,
    int R)
{
    __shared__ float mu[64];
    __shared__ float pairs[256];
    __shared__ float s0s[MOO], s1s[MOO];
    __shared__ float svals[256][9];
    __shared__ int   sidx[256][9];

    const int tid = threadIdx.x;
    const int b   = blockIdx.x;

    if (tid < 64) {
        int d = tid >> 3, c = tid & 7;
        float v = 1.0f;
        if (c < MM) {
            float z = (x[b * DD + d] - in_centers[d * MM + c]) / in_widths[d * MM + c];
            v = expf(-0.5f * z * z);
            v = fminf(v, 1.0f);
            v = fmaxf(v, EPSF);
        }
        mu[tid] = v;
    } else if (tid < 64 + MOO) {
        int mo = tid - 64;
        float oc = out_centers[mo], ow = out_widths[mo];
        float s0 = 0.0f, s1 = 0.0f;
        for (int p = 0; p < NPTS; ++p) {
            float u = (float)p * (1.0f / 99.0f);
            float z = (u - oc) / ow;
            float e = expf(-0.5f * z * z);
            s0 += e;
            s1 += u * e;
        }
        s0s[mo] = s0;
        s1s[mo] = s1;
    }
    __syncthreads();

    {
        int p = tid >> 6, q = tid & 63;
        pairs[tid] = mu[(2 * p) * 8 + (q & 7)] * mu[(2 * p + 1) * 8 + (q >> 3)];
    }
    __syncthreads();

    float vals[8];
    int   idxs[8];
    #pragma unroll
    for (int k = 0; k < 8; ++k) { vals[k] = -1.0f; idxs[k] = 0x7fffffff; }

    for (int r = tid; r < R; r += 256) {
        const int4* a = reinterpret_cast<const int4*>(ant) + (size_t)r * 2;
        int4 lo = a[0], hi = a[1];
        int v[8] = {lo.x, lo.y, lo.z, lo.w, hi.x, hi.y, hi.z, hi.w};
        unsigned code = 0u;
        #pragma unroll
        for (int i = 0; i < 8; ++i) {
            int c = v[i];
            c = (c < 0) ? 7 : (c > MM - 1 ? MM - 1 : c);
            code |= (unsigned)c << (3 * i);
        }
        float f = pairs[code & 63]
                * pairs[64  + ((code >> 6)  & 63)]
                * pairs[128 + ((code >> 12) & 63)]
                * pairs[192 + ((code >> 18) & 63)];
        if (f > vals[7]) {
            float nv = f; int ni = r;
            #pragma unroll
            for (int k = 0; k < 8; ++k) {
                bool take = nv > vals[k];
                float cv = vals[k]; int ci = idxs[k];
                vals[k] = take ? nv : cv;
                idxs[k] = take ? ni : ci;
                nv = take ? cv : nv;
                ni = take ? ci : ni;
            }
        }
    }

    #pragma unroll
    for (int k = 0; k < 8; ++k) { svals[tid][k] = vals[k]; sidx[tid][k] = idxs[k]; }

    for (int off = 128; off >= 1; off >>= 1) {
        __syncthreads();
        if (tid < off) {
            float ov[8]; int oi[8];
            int pa = 0, pb = 0;
            #pragma unroll
            for (int k = 0; k < 8; ++k) {
                float va = svals[tid][pa];        int ia = sidx[tid][pa];
                float vb = svals[tid + off][pb];  int ib = sidx[tid + off][pb];
                bool ta = (va > vb) || ((va == vb) && (ia < ib));
                ov[k] = ta ? va : vb;
                oi[k] = ta ? ia : ib;
                pa += ta ? 1 : 0;
                pb += ta ? 0 : 1;
            }
            #pragma unroll
            for (int k = 0; k < 8; ++k) { svals[tid][k] = ov[k]; sidx[tid][k] = oi[k]; }
        }
    }
    __syncthreads();

    if (tid == 0) {
        float num = 0.0f, den = 0.0f;
        #pragma unroll
        for (int k = 0; k < 8; ++k) {
            float v = svals[0][k];
            int   c = consequents[sidx[0][k]];
            num += v * s1s[c];
            den += v * s0s[c];
        }
        out[b] = num / (den + EPSF);
    }
}

extern "C" void kernel_launch(void* const* d_in, const int* in_sizes, int n_in,
                              void* d_out, int out_size, void* d_ws, size_t ws_size,
                              hipStream_t stream) {
    const float* x      = (const float*)d_in[0];
    const int*   ant    = (const int*)d_in[1];
    const int*   cons   = (const int*)d_in[2];
    const float* in_c   = (const float*)d_in[3];
    const float* in_w   = (const float*)d_in[4];
    const float* out_c  = (const float*)d_in[5];
    const float* out_w  = (const float*)d_in[6];
    float*       out    = (float*)d_out;

    const int B = in_sizes[0] / DD;
    const int R = in_sizes[1] / DD;

    const bool shape_ok = (R == THREADS * 4 * ITERS) && (B == NBLK * 4);
    // ws: codes (R*4) + thresholds (NBLK*4*4) + bitmaps (NBLK*4*16*8)
    const size_t need = (size_t)R * 4 + (size_t)NBLK * 4 * 4 + (size_t)NBLK * 4 * 16 * 8;

    if (shape_ok && d_ws && ws_size >= need) {
        unsigned* g_off = (unsigned*)d_ws;
        float*    g_thr = (float*)(g_off + R);
        unsigned long long* g_bitmap = (unsigned long long*)(g_thr + NBLK * 4);
        pack_kernel<<<(R + 255) / 256, 256, 0, stream>>>(ant, g_off, R);
        anfis_scan<<<NBLK, THREADS, 0, stream>>>(x, g_off, in_c, in_w, g_thr, g_bitmap);
        anfis_select<<<NBLK, THREADS, 0, stream>>>(x, g_off, cons, in_c, in_w,
                                                   out_c, out_w, g_thr, g_bitmap, out);
    } else {
        anfis_kernel<<<B, 256, 0, stream>>>(x, ant, cons, in_c, in_w,
                                            out_c, out_w, out, R);
    }
}

// Round 13
// 39.521 us; speedup vs baseline: 1.4685x; 1.4319x over previous
//
#include <hip/hip_runtime.h>
#include <math.h>

#define DD 8
#define MM 7
#define MOO 9
#define NPTS 100
#define EPSF 1e-5f

#define THREADS 1024
#define ITERS 8           // uint4 code loads per thread; THREADS*4*ITERS == 32768
#define ROWS 8            // batch rows per block
#define CAP 256           // candidate buffer capacity per row
#define WLCAP 8192        // worklist capacity == max possible items (no overflow)
// Truncated-bf16 one-sided bounds: f~ >= 0.992203*f, trunc(max f~) >= 0.988326*f.
#define THR_SLACK 0.9879f

__device__ __forceinline__ float bl(unsigned u) { return __uint_as_float(u << 16); }
__device__ __forceinline__ float bh(unsigned u) { return __uint_as_float(u & 0xFFFF0000u); }
__device__ __forceinline__ unsigned pkb(float a, float b) {
    return (__float_as_uint(b) & 0xFFFF0000u) | (__float_as_uint(a) >> 16);
}

// ---------------- pack: antecedents -> packed entry-offset word -------------
// (w & 0xFFFF) >> 3 = entry index into quad table 0 (dims 0-3)
// w >> 19          = entry index into quad table 1 (4096..8191, base pre-added)
__global__ __launch_bounds__(256) void pack_kernel(const int* __restrict__ ant,
                                                   unsigned* __restrict__ g_off,
                                                   int R) {
    int r = blockIdx.x * 256 + threadIdx.x;
    if (r < R) {
        const int4* a = reinterpret_cast<const int4*>(ant) + (size_t)r * 2;
        int4 lo = a[0], hi = a[1];
        int v[8] = {lo.x, lo.y, lo.z, lo.w, hi.x, hi.y, hi.z, hi.w};
        unsigned code = 0u;
        #pragma unroll
        for (int i = 0; i < 8; ++i) {
            int c = v[i];
            c = (c < 0) ? 7 : (c > MM - 1 ? MM - 1 : c);   // -1 -> wildcard slot 7
            code |= (unsigned)c << (3 * i);
        }
        g_off[r] = ((code & 4095u) << 3) | ((((code >> 12) << 3) + 32768u) << 16);
    }
}

// =================== KERNEL A: scan, 8 rows/block ===========================
// Quad tables hold 8 rows as truncated bf16 in uint4 (16B): one ds_read_b128
// serves 8 rows. 256 blocks = 1/CU = single generation; per-CU DS work for the
// whole batch drops ~2x vs R12. VALU:DS ~36:2 per rule hides LDS latency at
// 16 waves. Emits per-row threshold T + per-wave qualify ballots.
__global__ __launch_bounds__(THREADS, 4) void anfis_scan8(
    const float* __restrict__ x,
    const unsigned* __restrict__ stream_off,
    const float* __restrict__ in_centers,   // [D][M]
    const float* __restrict__ in_widths,    // [D][M]
    float* __restrict__ g_thr,              // [nblk*8]
    unsigned long long* __restrict__ g_bitmap)  // [nblk*8*16]
{
    __shared__ uint4 quads[8192];        // 128 KB: 2 tables x 4096, bf16x8 rows
    __shared__ float mu[ROWS][64];       // 2 KB
    __shared__ float pairs[ROWS][256];   // 8 KB exact f32 pair products
    __shared__ uint4 smaxpk[THREADS];    // 16 KB packed thread maxes
    __shared__ float sT[ROWS];

    const int tid = threadIdx.x;
    const int b0  = blockIdx.x * ROWS;

    // --- phase 0: membership tables (8 rows) ---
    if (tid < 512) {
        int row = tid >> 6, d = (tid >> 3) & 7, c = tid & 7;
        float v = 1.0f;
        if (c < MM) {
            float z = (x[(b0 + row) * DD + d] - in_centers[d * MM + c]) / in_widths[d * MM + c];
            v = expf(-0.5f * z * z);
            v = fminf(v, 1.0f);
            v = fmaxf(v, EPSF);
        }
        mu[row][(d << 3) + c] = v;
    }
    __syncthreads();

    // --- phase 1: exact pair products (2048 entries, 2/thread) ---
    #pragma unroll
    for (int i = 0; i < 2; ++i) {
        int k = tid + i * THREADS;
        int row = k >> 8, e = k & 255;
        int p = e >> 6, q = e & 63;
        pairs[row][e] = mu[row][(2 * p) * 8 + (q & 7)] * mu[row][(2 * p + 1) * 8 + (q >> 3)];
    }
    __syncthreads();

    // --- phase 2: quad tables, truncated bf16 x 8 rows per 16B entry ---
    #pragma unroll
    for (int i = 0; i < 8; ++i) {
        int k = tid + i * THREADS;
        int t = k & 4095, h = k >> 12;
        int ia = h * 128 + (t & 63), ib = h * 128 + 64 + ((t >> 6) & 63);
        float q0 = pairs[0][ia] * pairs[0][ib];
        float q1 = pairs[1][ia] * pairs[1][ib];
        float q2 = pairs[2][ia] * pairs[2][ib];
        float q3 = pairs[3][ia] * pairs[3][ib];
        float q4 = pairs[4][ia] * pairs[4][ib];
        float q5 = pairs[5][ia] * pairs[5][ib];
        float q6 = pairs[6][ia] * pairs[6][ib];
        float q7 = pairs[7][ia] * pairs[7][ib];
        quads[k] = make_uint4(pkb(q0, q1), pkb(q2, q3), pkb(q4, q5), pkb(q6, q7));
    }
    __syncthreads();

    // --- phase 3: scan all rules; each ds_read_b128 pair serves 8 rows ---
    const uint4* pk4 = reinterpret_cast<const uint4*>(stream_off);
    float m[ROWS];
    #pragma unroll
    for (int r = 0; r < ROWS; ++r) m[r] = -1.0f;
    #pragma unroll
    for (int j = 0; j < ITERS; ++j) {
        uint4 cd = pk4[j * THREADS + tid];
        unsigned wv_[4] = {cd.x, cd.y, cd.z, cd.w};
        #pragma unroll
        for (int s = 0; s < 4; ++s) {
            unsigned w = wv_[s];
            uint4 eA = quads[(w & 0xFFFFu) >> 3];
            uint4 eB = quads[w >> 19];
            m[0] = fmaxf(m[0], bl(eA.x) * bl(eB.x));
            m[1] = fmaxf(m[1], bh(eA.x) * bh(eB.x));
            m[2] = fmaxf(m[2], bl(eA.y) * bl(eB.y));
            m[3] = fmaxf(m[3], bh(eA.y) * bh(eB.y));
            m[4] = fmaxf(m[4], bl(eA.z) * bl(eB.z));
            m[5] = fmaxf(m[5], bh(eA.z) * bh(eB.z));
            m[6] = fmaxf(m[6], bl(eA.w) * bl(eB.w));
            m[7] = fmaxf(m[7], bh(eA.w) * bh(eB.w));
        }
    }
    smaxpk[tid] = make_uint4(pkb(m[0], m[1]), pkb(m[2], m[3]),
                             pkb(m[4], m[5]), pkb(m[6], m[7]));
    __syncthreads();

    // --- phase 4: wave w (w<8) extracts 8th-largest packed thread-max ---
    if (tid < 512) {
        int row = tid >> 6, lane = tid & 63;
        float mm[16];
        #pragma unroll
        for (int k = 0; k < 16; ++k) {
            uint4 e = smaxpk[lane + 64 * k];
            unsigned word = (row & 4) ? ((row & 2) ? e.w : e.z)
                                      : ((row & 2) ? e.y : e.x);
            mm[k] = (row & 1) ? bh(word) : bl(word);
        }
        float thr = -1.0f;
        #pragma unroll
        for (int round = 0; round < 8; ++round) {
            float lm = mm[0];
            #pragma unroll
            for (int k = 1; k < 16; ++k) lm = fmaxf(lm, mm[k]);
            float wm = lm;
            #pragma unroll
            for (int off = 32; off >= 1; off >>= 1)
                wm = fmaxf(wm, __shfl_xor(wm, off, 64));
            unsigned long long bal = __ballot(lm == wm);
            int first = (int)__ffsll(bal) - 1;
            if (lane == first) {                // remove exactly one instance
                bool done = false;
                #pragma unroll
                for (int k = 0; k < 16; ++k) {
                    bool rm = (!done) && (mm[k] == wm);
                    mm[k] = rm ? -2.0f : mm[k];
                    done = done || rm;
                }
            }
            thr = wm;
        }
        if (lane == 0) sT[row] = thr;
    }
    __syncthreads();

    // --- emit thresholds + per-wave qualify ballots ---
    {
        const int wid = tid >> 6, lane = tid & 63;
        #pragma unroll
        for (int row = 0; row < ROWS; ++row) {
            unsigned long long bal = __ballot(m[row] >= THR_SLACK * sT[row]);
            if (lane == 0)
                g_bitmap[((size_t)blockIdx.x * ROWS + row) * 16 + wid] = bal;
        }
        if (tid < ROWS) g_thr[blockIdx.x * ROWS + tid] = sT[tid];
    }
}

// =================== KERNEL B: select via compacted worklist ================
// Bitmaps -> worklist of (row, thread) items; each item is processed by a
// HALF-WAVE (32 lanes = the thread's 32 rules, one per lane) -> no dense
// exec-masked rescan. Exact f32 recompute + exact (val desc, idx asc).
__global__ __launch_bounds__(THREADS, 8) void anfis_select8(
    const float* __restrict__ x,
    const unsigned* __restrict__ stream_off,
    const int* __restrict__ consequents,
    const float* __restrict__ in_centers,
    const float* __restrict__ in_widths,
    const float* __restrict__ out_centers,
    const float* __restrict__ out_widths,
    const float* __restrict__ g_thr,
    const unsigned long long* __restrict__ g_bitmap,
    float* __restrict__ out)
{
    __shared__ float mu[ROWS][64];
    __shared__ float pairs[ROWS][256];
    __shared__ float s0s[MOO], s1s[MOO];
    __shared__ float sT[ROWS];
    __shared__ int   wl[WLCAP];
    __shared__ int   wlcnt;
    __shared__ float cvals[ROWS][CAP];
    __shared__ int   cidx[ROWS][CAP];
    __shared__ int   scnt[ROWS];
    __shared__ float wv[ROWS][8];
    __shared__ int   wc[ROWS][8];

    const int tid = threadIdx.x;
    const int b0  = blockIdx.x * ROWS;

    // --- phase 0: membership + defuzz constants + loads/init ---
    if (tid < 512) {
        int row = tid >> 6, d = (tid >> 3) & 7, c = tid & 7;
        float v = 1.0f;
        if (c < MM) {
            float z = (x[(b0 + row) * DD + d] - in_centers[d * MM + c]) / in_widths[d * MM + c];
            v = expf(-0.5f * z * z);
            v = fminf(v, 1.0f);
            v = fmaxf(v, EPSF);
        }
        mu[row][(d << 3) + c] = v;
    } else if (tid < 512 + MOO) {
        int mo = tid - 512;
        float oc = out_centers[mo], ow = out_widths[mo];
        float s0 = 0.0f, s1 = 0.0f;
        for (int p = 0; p < NPTS; ++p) {
            float u = (float)p * (1.0f / 99.0f);
            float z = (u - oc) / ow;
            float e = expf(-0.5f * z * z);
            s0 += e;
            s1 += u * e;
        }
        s0s[mo] = s0;
        s1s[mo] = s1;
    } else if (tid >= 544 && tid < 544 + ROWS) {
        sT[tid - 544] = g_thr[blockIdx.x * ROWS + (tid - 544)];
    } else if (tid >= 576 && tid < 576 + ROWS) {
        scnt[tid - 576] = 0;
    } else if (tid == 600) {
        wlcnt = 0;
    }
    __syncthreads();

    // --- phase 1: exact pair products ---
    #pragma unroll
    for (int i = 0; i < 2; ++i) {
        int k = tid + i * THREADS;
        int row = k >> 8, e = k & 255;
        int p = e >> 6, q = e & 63;
        pairs[row][e] = mu[row][(2 * p) * 8 + (q & 7)] * mu[row][(2 * p + 1) * 8 + (q >> 3)];
    }
    __syncthreads();

    // --- phase 2: build compacted worklist from bitmaps ---
    {
        const int wid = tid >> 6, lane = tid & 63;
        #pragma unroll
        for (int row = 0; row < ROWS; ++row) {
            unsigned long long bal = g_bitmap[((size_t)blockIdx.x * ROWS + row) * 16 + wid];
            if ((bal >> lane) & 1ull) {
                int pos = atomicAdd(&wlcnt, 1);
                wl[pos] = (row << 10) | tid;       // WLCAP == max items, no overflow
            }
        }
    }
    __syncthreads();

    // --- phase 3: half-wave per item; lane = one of the thread's 32 rules ---
    {
        const int wid = tid >> 6, lane = tid & 63;
        const int hl = lane & 31;                  // rule slot within item
        const int j = hl >> 2, s = hl & 3;
        const int n = wlcnt;
        for (int i = wid * 2 + (lane >> 5); i < n; i += 32) {
            int it  = wl[i];
            int row = it >> 10;
            int t   = it & 1023;
            int flat = (j * THREADS + t) * 4 + s;
            unsigned w = stream_off[flat];
            unsigned lo12 = (w & 0xFFFFu) >> 3;
            unsigned hi12 = (w >> 19) - 4096u;
            const float* P = pairs[row];
            float f = (P[lo12 & 63u] * P[64 + (lo12 >> 6)])
                    * (P[128 + (hi12 & 63u)] * P[192 + (hi12 >> 6)]);
            if (f >= sT[row]) {
                int pos = atomicAdd(&scnt[row], 1);
                if (pos < CAP) {
                    cvals[row][pos] = f;
                    cidx[row][pos]  = flat;
                }
            }
        }
    }
    __syncthreads();

    // --- phase 4: exact rank selection per row (val desc, orig idx asc) ---
    if (tid < 512) {
        int row = tid >> 6, lane = tid & 63;
        int n = scnt[row] < CAP ? scnt[row] : CAP;
        for (int c = lane; c < n; c += 64) {
            float v  = cvals[row][c];
            int   id = cidx[row][c];
            int rk = 0;
            for (int mI = 0; mI < n; ++mI) {
                float vm = cvals[row][mI];
                int   im = cidx[row][mI];
                rk += ((vm > v) || (vm == v && im < id)) ? 1 : 0;
            }
            if (rk < 8) {
                wv[row][rk] = v;
                wc[row][rk] = consequents[id];
            }
        }
    }
    __syncthreads();

    // --- phase 5: defuzzify ---
    if (tid < ROWS) {
        int row = tid;
        float num = 0.0f, den = 0.0f;
        #pragma unroll
        for (int k = 0; k < 8; ++k) {
            num += wv[row][k] * s1s[wc[row][k]];
            den += wv[row][k] * s0s[wc[row][k]];
        }
        out[b0 + row] = num / (den + EPSF);
    }
}

// ---------------- generic fallback (round-1 kernel, inline pack) ------------
__global__ __launch_bounds__(256) void anfis_kernel(
    const float* __restrict__ x,
    const int* __restrict__ ant,
    const int* __restrict__ consequents,
    const float* __restrict__ in_centers,
    const float* __restrict__ in_widths,
    const float* __restrict__ out_centers,
    const float* __restrict__ out_widths,
    float* __restrict__ out,
    int R)
{
    __shared__ float mu[64];
    __shared__ float pairs[256];
    __shared__ float s0s[MOO], s1s[MOO];
    __shared__ float svals[256][9];
    __shared__ int   sidx[256][9];

    const int tid = threadIdx.x;
    const int b   = blockIdx.x;

    if (tid < 64) {
        int d = tid >> 3, c = tid & 7;
        float v = 1.0f;
        if (c < MM) {
            float z = (x[b * DD + d] - in_centers[d * MM + c]) / in_widths[d * MM + c];
            v = expf(-0.5f * z * z);
            v = fminf(v, 1.0f);
            v = fmaxf(v, EPSF);
        }
        mu[tid] = v;
    } else if (tid < 64 + MOO) {
        int mo = tid - 64;
        float oc = out_centers[mo], ow = out_widths[mo];
        float s0 = 0.0f, s1 = 0.0f;
        for (int p = 0; p < NPTS; ++p) {
            float u = (float)p * (1.0f / 99.0f);
            float z = (u - oc) / ow;
            float e = expf(-0.5f * z * z);
            s0 += e;
            s1 += u * e;
        }
        s0s[mo] = s0;
        s1s[mo] = s1;
    }
    __syncthreads();

    {
        int p = tid >> 6, q = tid & 63;
        pairs[tid] = mu[(2 * p) * 8 + (q & 7)] * mu[(2 * p + 1) * 8 + (q >> 3)];
    }
    __syncthreads();

    float vals[8];
    int   idxs[8];
    #pragma unroll
    for (int k = 0; k < 8; ++k) { vals[k] = -1.0f; idxs[k] = 0x7fffffff; }

    for (int r = tid; r < R; r += 256) {
        const int4* a = reinterpret_cast<const int4*>(ant) + (size_t)r * 2;
        int4 lo = a[0], hi = a[1];
        int v[8] = {lo.x, lo.y, lo.z, lo.w, hi.x, hi.y, hi.z, hi.w};
        unsigned code = 0u;
        #pragma unroll
        for (int i = 0; i < 8; ++i) {
            int c = v[i];
            c = (c < 0) ? 7 : (c > MM - 1 ? MM - 1 : c);
            code |= (unsigned)c << (3 * i);
        }
        float f = pairs[code & 63]
                * pairs[64  + ((code >> 6)  & 63)]
                * pairs[128 + ((code >> 12) & 63)]
                * pairs[192 + ((code >> 18) & 63)];
        if (f > vals[7]) {
            float nv = f; int ni = r;
            #pragma unroll
            for (int k = 0; k < 8; ++k) {
                bool take = nv > vals[k];
                float cv = vals[k]; int ci = idxs[k];
                vals[k] = take ? nv : cv;
                idxs[k] = take ? ni : ci;
                nv = take ? cv : nv;
                ni = take ? ci : ni;
            }
        }
    }

    #pragma unroll
    for (int k = 0; k < 8; ++k) { svals[tid][k] = vals[k]; sidx[tid][k] = idxs[k]; }

    for (int off = 128; off >= 1; off >>= 1) {
        __syncthreads();
        if (tid < off) {
            float ov[8]; int oi[8];
            int pa = 0, pb = 0;
            #pragma unroll
            for (int k = 0; k < 8; ++k) {
                float va = svals[tid][pa];        int ia = sidx[tid][pa];
                float vb = svals[tid + off][pb];  int ib = sidx[tid + off][pb];
                bool ta = (va > vb) || ((va == vb) && (ia < ib));
                ov[k] = ta ? va : vb;
                oi[k] = ta ? ia : ib;
                pa += ta ? 1 : 0;
                pb += ta ? 0 : 1;
            }
            #pragma unroll
            for (int k = 0; k < 8; ++k) { svals[tid][k] = ov[k]; sidx[tid][k] = oi[k]; }
        }
    }
    __syncthreads();

    if (tid == 0) {
        float num = 0.0f, den = 0.0f;
        #pragma unroll
        for (int k = 0; k < 8; ++k) {
            float v = svals[0][k];
            int   c = consequents[sidx[0][k]];
            num += v * s1s[c];
            den += v * s0s[c];
        }
        out[b] = num / (den + EPSF);
    }
}

extern "C" void kernel_launch(void* const* d_in, const int* in_sizes, int n_in,
                              void* d_out, int out_size, void* d_ws, size_t ws_size,
                              hipStream_t stream) {
    const float* x      = (const float*)d_in[0];
    const int*   ant    = (const int*)d_in[1];
    const int*   cons   = (const int*)d_in[2];
    const float* in_c   = (const float*)d_in[3];
    const float* in_w   = (const float*)d_in[4];
    const float* out_c  = (const float*)d_in[5];
    const float* out_w  = (const float*)d_in[6];
    float*       out    = (float*)d_out;

    const int B = in_sizes[0] / DD;
    const int R = in_sizes[1] / DD;

    const int nblk = B / ROWS;
    const bool shape_ok = (R == THREADS * 4 * ITERS) && (B % ROWS == 0);
    // ws: codes (R*4) + thresholds (nblk*8*4) + bitmaps (nblk*8*16*8)
    const size_t need = (size_t)R * 4 + (size_t)nblk * ROWS * 4
                      + (size_t)nblk * ROWS * 16 * 8;

    if (shape_ok && d_ws && ws_size >= need) {
        unsigned* g_off = (unsigned*)d_ws;
        float*    g_thr = (float*)(g_off + R);
        unsigned long long* g_bitmap = (unsigned long long*)(g_thr + nblk * ROWS);
        pack_kernel<<<(R + 255) / 256, 256, 0, stream>>>(ant, g_off, R);
        anfis_scan8<<<nblk, THREADS, 0, stream>>>(x, g_off, in_c, in_w, g_thr, g_bitmap);
        anfis_select8<<<nblk, THREADS, 0, stream>>>(x, g_off, cons, in_c, in_w,
                                                    out_c, out_w, g_thr, g_bitmap, out);
    } else {
        anfis_kernel<<<B, 256, 0, stream>>>(x, ant, cons, in_c, in_w,
                                            out_c, out_w, out, R);
    }
}

// Round 14
// 36.157 us; speedup vs baseline: 1.6051x; 1.0930x over previous
//
#include <hip/hip_runtime.h>
#include <math.h>

#define DD 8
#define MM 7
#define MOO 9
#define NPTS 100
#define EPSF 1e-5f

#define THREADS 1024
#define ITERS 8           // uint4 code loads per thread; THREADS*4*ITERS == 32768
#define ROWS 8            // batch rows per block
#define CAP 256           // candidate buffer capacity per row
// Truncated-bf16 one-sided bounds: f~ >= 0.992203*f, trunc(max f~) >= 0.988326*f.
#define THR_SLACK 0.9879f

__device__ __forceinline__ float bl(unsigned u) { return __uint_as_float(u << 16); }
__device__ __forceinline__ float bh(unsigned u) { return __uint_as_float(u & 0xFFFF0000u); }
__device__ __forceinline__ unsigned pkb(float a, float b) {
    return (__float_as_uint(b) & 0xFFFF0000u) | (__float_as_uint(a) >> 16);
}

// ---------------- pack: antecedents -> packed entry-offset word -------------
// (w & 0xFFFF) >> 3 = entry index into quad table 0 (dims 0-3)
// w >> 19          = entry index into quad table 1 (4096..8191, base pre-added)
__global__ __launch_bounds__(256) void pack_kernel(const int* __restrict__ ant,
                                                   unsigned* __restrict__ g_off,
                                                   int R) {
    int r = blockIdx.x * 256 + threadIdx.x;
    if (r < R) {
        const int4* a = reinterpret_cast<const int4*>(ant) + (size_t)r * 2;
        int4 lo = a[0], hi = a[1];
        int v[8] = {lo.x, lo.y, lo.z, lo.w, hi.x, hi.y, hi.z, hi.w};
        unsigned code = 0u;
        #pragma unroll
        for (int i = 0; i < 8; ++i) {
            int c = v[i];
            c = (c < 0) ? 7 : (c > MM - 1 ? MM - 1 : c);   // -1 -> wildcard slot 7
            code |= (unsigned)c << (3 * i);
        }
        g_off[r] = ((code & 4095u) << 3) | ((((code >> 12) << 3) + 32768u) << 16);
    }
}

// =================== fused kernel: 8 rows/block, scan + select ==============
// R13 scan8 + in-kernel select: quads (128 KB) are DEAD after phase 3, so the
// worklist (ushort, 16 KB) and candidate buffers (16 KB) alias its storage.
// Removes the bitmap round-trip, select8's launch gap, and its mu/pairs
// rebuild (~6-10 us of R13's total).
__global__ __launch_bounds__(THREADS, 4) void anfis_fused8(
    const float* __restrict__ x,
    const unsigned* __restrict__ stream_off,
    const int* __restrict__ consequents,
    const float* __restrict__ in_centers,   // [D][M]
    const float* __restrict__ in_widths,    // [D][M]
    const float* __restrict__ out_centers,  // [MO]
    const float* __restrict__ out_widths,   // [MO]
    float* __restrict__ out)
{
    __shared__ uint4 quads[8192];        // 128 KB; aliased after phase 3:
                                         //   bytes [0,16K):  ushort wl[8192]
                                         //   bytes [16K,24K): float cvals[8][256]
                                         //   bytes [24K,32K): int   cidx[8][256]
    __shared__ float mu[ROWS][64];       // 2 KB
    __shared__ float pairs[ROWS][256];   // 8 KB exact f32 pair products
    __shared__ uint4 smaxpk[THREADS];    // 16 KB packed thread maxes
    __shared__ float s0s[MOO], s1s[MOO];
    __shared__ float sT[ROWS];
    __shared__ int   scnt[ROWS];
    __shared__ int   wlcnt;
    __shared__ float wv[ROWS][8];
    __shared__ int   wc[ROWS][8];

    const int tid = threadIdx.x;
    const int b0  = blockIdx.x * ROWS;

    unsigned short* wl = (unsigned short*)quads;          // 16 KB
    float* cvals = (float*)(quads + 1024);                // 8 KB  @16K
    int*   cidx  = (int*)(quads + 1536);                  // 8 KB  @24K

    // --- phase 0: membership tables (8 rows) + defuzz constants + init ---
    if (tid < 512) {
        int row = tid >> 6, d = (tid >> 3) & 7, c = tid & 7;
        float v = 1.0f;
        if (c < MM) {
            float z = (x[(b0 + row) * DD + d] - in_centers[d * MM + c]) / in_widths[d * MM + c];
            v = expf(-0.5f * z * z);
            v = fminf(v, 1.0f);
            v = fmaxf(v, EPSF);
        }
        mu[row][(d << 3) + c] = v;
    } else if (tid < 512 + MOO) {
        int mo = tid - 512;
        float oc = out_centers[mo], ow = out_widths[mo];
        float s0 = 0.0f, s1 = 0.0f;
        for (int p = 0; p < NPTS; ++p) {
            float u = (float)p * (1.0f / 99.0f);
            float z = (u - oc) / ow;
            float e = expf(-0.5f * z * z);
            s0 += e;
            s1 += u * e;
        }
        s0s[mo] = s0;
        s1s[mo] = s1;
    } else if (tid >= 544 && tid < 544 + ROWS) {
        scnt[tid - 544] = 0;
    } else if (tid == 560) {
        wlcnt = 0;
    }
    __syncthreads();

    // --- phase 1: exact pair products (2048 entries, 2/thread) ---
    #pragma unroll
    for (int i = 0; i < 2; ++i) {
        int k = tid + i * THREADS;
        int row = k >> 8, e = k & 255;
        int p = e >> 6, q = e & 63;
        pairs[row][e] = mu[row][(2 * p) * 8 + (q & 7)] * mu[row][(2 * p + 1) * 8 + (q >> 3)];
    }
    __syncthreads();

    // --- phase 2: quad tables, truncated bf16 x 8 rows per 16B entry ---
    #pragma unroll
    for (int i = 0; i < 8; ++i) {
        int k = tid + i * THREADS;
        int t = k & 4095, h = k >> 12;
        int ia = h * 128 + (t & 63), ib = h * 128 + 64 + ((t >> 6) & 63);
        float q0 = pairs[0][ia] * pairs[0][ib];
        float q1 = pairs[1][ia] * pairs[1][ib];
        float q2 = pairs[2][ia] * pairs[2][ib];
        float q3 = pairs[3][ia] * pairs[3][ib];
        float q4 = pairs[4][ia] * pairs[4][ib];
        float q5 = pairs[5][ia] * pairs[5][ib];
        float q6 = pairs[6][ia] * pairs[6][ib];
        float q7 = pairs[7][ia] * pairs[7][ib];
        quads[k] = make_uint4(pkb(q0, q1), pkb(q2, q3), pkb(q4, q5), pkb(q6, q7));
    }
    __syncthreads();

    // --- phase 3: scan all rules; each ds_read_b128 pair serves 8 rows ---
    const uint4* pk4 = reinterpret_cast<const uint4*>(stream_off);
    float m[ROWS];
    #pragma unroll
    for (int r = 0; r < ROWS; ++r) m[r] = -1.0f;
    #pragma unroll
    for (int j = 0; j < ITERS; ++j) {
        uint4 cd = pk4[j * THREADS + tid];
        unsigned wrd[4] = {cd.x, cd.y, cd.z, cd.w};
        #pragma unroll
        for (int s = 0; s < 4; ++s) {
            unsigned w = wrd[s];
            uint4 eA = quads[(w & 0xFFFFu) >> 3];
            uint4 eB = quads[w >> 19];
            m[0] = fmaxf(m[0], bl(eA.x) * bl(eB.x));
            m[1] = fmaxf(m[1], bh(eA.x) * bh(eB.x));
            m[2] = fmaxf(m[2], bl(eA.y) * bl(eB.y));
            m[3] = fmaxf(m[3], bh(eA.y) * bh(eB.y));
            m[4] = fmaxf(m[4], bl(eA.z) * bl(eB.z));
            m[5] = fmaxf(m[5], bh(eA.z) * bh(eB.z));
            m[6] = fmaxf(m[6], bl(eA.w) * bl(eB.w));
            m[7] = fmaxf(m[7], bh(eA.w) * bh(eB.w));
        }
    }
    smaxpk[tid] = make_uint4(pkb(m[0], m[1]), pkb(m[2], m[3]),
                             pkb(m[4], m[5]), pkb(m[6], m[7]));
    __syncthreads();          // quads DEAD from here on

    // --- phase 4: wave w (w<8) extracts 8th-largest packed thread-max ---
    if (tid < 512) {
        int row = tid >> 6, lane = tid & 63;
        float mm[16];
        #pragma unroll
        for (int k = 0; k < 16; ++k) {
            uint4 e = smaxpk[lane + 64 * k];
            unsigned word = (row & 4) ? ((row & 2) ? e.w : e.z)
                                      : ((row & 2) ? e.y : e.x);
            mm[k] = (row & 1) ? bh(word) : bl(word);
        }
        float thr = -1.0f;
        #pragma unroll
        for (int round = 0; round < 8; ++round) {
            float lm = mm[0];
            #pragma unroll
            for (int k = 1; k < 16; ++k) lm = fmaxf(lm, mm[k]);
            float wm = lm;
            #pragma unroll
            for (int off = 32; off >= 1; off >>= 1)
                wm = fmaxf(wm, __shfl_xor(wm, off, 64));
            unsigned long long bal = __ballot(lm == wm);
            int first = (int)__ffsll(bal) - 1;
            if (lane == first) {                // remove exactly one instance
                bool done = false;
                #pragma unroll
                for (int k = 0; k < 16; ++k) {
                    bool rm = (!done) && (mm[k] == wm);
                    mm[k] = rm ? -2.0f : mm[k];
                    done = done || rm;
                }
            }
            thr = wm;
        }
        if (lane == 0) sT[row] = thr;
    }
    __syncthreads();

    // --- phase 5: build compacted worklist from register maxes ---
    {
        #pragma unroll
        for (int row = 0; row < ROWS; ++row) {
            if (m[row] >= THR_SLACK * sT[row]) {
                int pos = atomicAdd(&wlcnt, 1);
                wl[pos] = (unsigned short)((row << 10) | tid);   // max 8192 items
            }
        }
    }
    __syncthreads();

    // --- phase 6: half-wave per item; lane = one of the thread's 32 rules ---
    {
        const int hl = tid & 31;                   // rule slot within item
        const int j = hl >> 2, s = hl & 3;
        const int n = wlcnt;
        for (int i = (tid >> 5); i < n; i += 32) {
            int it  = wl[i];
            int row = it >> 10;
            int t   = it & 1023;
            int flat = (j * THREADS + t) * 4 + s;
            unsigned w = stream_off[flat];
            unsigned lo12 = (w & 0xFFFFu) >> 3;
            unsigned hi12 = (w >> 19) - 4096u;
            const float* P = pairs[row];
            float f = (P[lo12 & 63u] * P[64 + (lo12 >> 6)])
                    * (P[128 + (hi12 & 63u)] * P[192 + (hi12 >> 6)]);
            if (f >= sT[row]) {
                int pos = atomicAdd(&scnt[row], 1);
                if (pos < CAP) {
                    cvals[row * CAP + pos] = f;
                    cidx[row * CAP + pos]  = flat;
                }
            }
        }
    }
    __syncthreads();

    // --- phase 7: exact rank selection per row (val desc, orig idx asc) ---
    if (tid < 512) {
        int row = tid >> 6, lane = tid & 63;
        int n = scnt[row] < CAP ? scnt[row] : CAP;
        for (int c = lane; c < n; c += 64) {
            float v  = cvals[row * CAP + c];
            int   id = cidx[row * CAP + c];
            int rk = 0;
            for (int mI = 0; mI < n; ++mI) {
                float vm = cvals[row * CAP + mI];
                int   im = cidx[row * CAP + mI];
                rk += ((vm > v) || (vm == v && im < id)) ? 1 : 0;
            }
            if (rk < 8) {
                wv[row][rk] = v;
                wc[row][rk] = consequents[id];
            }
        }
    }
    __syncthreads();

    // --- phase 8: defuzzify ---
    if (tid < ROWS) {
        int row = tid;
        float num = 0.0f, den = 0.0f;
        #pragma unroll
        for (int k = 0; k < 8; ++k) {
            num += wv[row][k] * s1s[wc[row][k]];
            den += wv[row][k] * s0s[wc[row][k]];
        }
        out[b0 + row] = num / (den + EPSF);
    }
}

// ---------------- generic fallback (round-1 kernel, inline pack) ------------
__global__ __launch_bounds__(256) void anfis_kernel(
    const float* __restrict__ x,
    const int* __restrict__ ant,
    const int* __restrict__ consequents,
    const float* __restrict__ in_centers,
    const float* __restrict__ in_widths,
    const float* __restrict__ out_centers,
    const float* __restrict__ out_widths,
    float* __restrict__ out,
    int R)
{
    __shared__ float mu[64];
    __shared__ float pairs[256];
    __shared__ float s0s[MOO], s1s[MOO];
    __shared__ float svals[256][9];
    __shared__ int   sidx[256][9];

    const int tid = threadIdx.x;
    const int b   = blockIdx.x;

    if (tid < 64) {
        int d = tid >> 3, c = tid & 7;
        float v = 1.0f;
        if (c < MM) {
            float z = (x[b * DD + d] - in_centers[d * MM + c]) / in_widths[d * MM + c];
            v = expf(-0.5f * z * z);
            v = fminf(v, 1.0f);
            v = fmaxf(v, EPSF);
        }
        mu[tid] = v;
    } else if (tid < 64 + MOO) {
        int mo = tid - 64;
        float oc = out_centers[mo], ow = out_widths[mo];
        float s0 = 0.0f, s1 = 0.0f;
        for (int p = 0; p < NPTS; ++p) {
            float u = (float)p * (1.0f / 99.0f);
            float z = (u - oc) / ow;
            float e = expf(-0.5f * z * z);
            s0 += e;
            s1 += u * e;
        }
        s0s[mo] = s0;
        s1s[mo] = s1;
    }
    __syncthreads();

    {
        int p = tid >> 6, q = tid & 63;
        pairs[tid] = mu[(2 * p) * 8 + (q & 7)] * mu[(2 * p + 1) * 8 + (q >> 3)];
    }
    __syncthreads();

    float vals[8];
    int   idxs[8];
    #pragma unroll
    for (int k = 0; k < 8; ++k) { vals[k] = -1.0f; idxs[k] = 0x7fffffff; }

    for (int r = tid; r < R; r += 256) {
        const int4* a = reinterpret_cast<const int4*>(ant) + (size_t)r * 2;
        int4 lo = a[0], hi = a[1];
        int v[8] = {lo.x, lo.y, lo.z, lo.w, hi.x, hi.y, hi.z, hi.w};
        unsigned code = 0u;
        #pragma unroll
        for (int i = 0; i < 8; ++i) {
            int c = v[i];
            c = (c < 0) ? 7 : (c > MM - 1 ? MM - 1 : c);
            code |= (unsigned)c << (3 * i);
        }
        float f = pairs[code & 63]
                * pairs[64  + ((code >> 6)  & 63)]
                * pairs[128 + ((code >> 12) & 63)]
                * pairs[192 + ((code >> 18) & 63)];
        if (f > vals[7]) {
            float nv = f; int ni = r;
            #pragma unroll
            for (int k = 0; k < 8; ++k) {
                bool take = nv > vals[k];
                float cv = vals[k]; int ci = idxs[k];
                vals[k] = take ? nv : cv;
                idxs[k] = take ? ni : ci;
                nv = take ? cv : nv;
                ni = take ? ci : ni;
            }
        }
    }

    #pragma unroll
    for (int k = 0; k < 8; ++k) { svals[tid][k] = vals[k]; sidx[tid][k] = idxs[k]; }

    for (int off = 128; off >= 1; off >>= 1) {
        __syncthreads();
        if (tid < off) {
            float ov[8]; int oi[8];
            int pa = 0, pb = 0;
            #pragma unroll
            for (int k = 0; k < 8; ++k) {
                float va = svals[tid][pa];        int ia = sidx[tid][pa];
                float vb = svals[tid + off][pb];  int ib = sidx[tid + off][pb];
                bool ta = (va > vb) || ((va == vb) && (ia < ib));
                ov[k] = ta ? va : vb;
                oi[k] = ta ? ia : ib;
                pa += ta ? 1 : 0;
                pb += ta ? 0 : 1;
            }
            #pragma unroll
            for (int k = 0; k < 8; ++k) { svals[tid][k] = ov[k]; sidx[tid][k] = oi[k]; }
        }
    }
    __syncthreads();

    if (tid == 0) {
        float num = 0.0f, den = 0.0f;
        #pragma unroll
        for (int k = 0; k < 8; ++k) {
            float v = svals[0][k];
            int   c = consequents[sidx[0][k]];
            num += v * s1s[c];
            den += v * s0s[c];
        }
        out[b] = num / (den + EPSF);
    }
}

extern "C" void kernel_launch(void* const* d_in, const int* in_sizes, int n_in,
                              void* d_out, int out_size, void* d_ws, size_t ws_size,
                              hipStream_t stream) {
    const float* x      = (const float*)d_in[0];
    const int*   ant    = (const int*)d_in[1];
    const int*   cons   = (const int*)d_in[2];
    const float* in_c   = (const float*)d_in[3];
    const float* in_w   = (const float*)d_in[4];
    const float* out_c  = (const float*)d_in[5];
    const float* out_w  = (const float*)d_in[6];
    float*       out    = (float*)d_out;

    const int B = in_sizes[0] / DD;
    const int R = in_sizes[1] / DD;

    const bool shape_ok = (R == THREADS * 4 * ITERS) && (B % ROWS == 0);
    const size_t need = (size_t)R * 4;    // packed words only

    if (shape_ok && d_ws && ws_size >= need) {
        unsigned* g_off = (unsigned*)d_ws;
        pack_kernel<<<(R + 255) / 256, 256, 0, stream>>>(ant, g_off, R);
        anfis_fused8<<<B / ROWS, THREADS, 0, stream>>>(x, g_off, cons, in_c, in_w,
                                                       out_c, out_w, out);
    } else {
        anfis_kernel<<<B, 256, 0, stream>>>(x, ant, cons, in_c, in_w,
                                            out_c, out_w, out, R);
    }
}

// Round 15
// 32.804 us; speedup vs baseline: 1.7692x; 1.1022x over previous
//
#include <hip/hip_runtime.h>
#include <math.h>

#define DD 8
#define MM 7
#define MOO 9
#define NPTS 100
#define EPSF 1e-5f

#define THREADS 1024
#define ITERS 8           // uint4 code loads per thread; THREADS*4*ITERS == 32768
#define ROWS 8            // batch rows per block
#define CAP 256           // candidate buffer capacity per row
// Truncated-bf16 one-sided bounds: f~ >= 0.992203*f, trunc(max f~) >= 0.988326*f.
#define THR_SLACK 0.9879f

typedef unsigned uint32x4 __attribute__((ext_vector_type(4)));

__device__ __forceinline__ float bl(unsigned u) { return __uint_as_float(u << 16); }
__device__ __forceinline__ float bh(unsigned u) { return __uint_as_float(u & 0xFFFF0000u); }
__device__ __forceinline__ unsigned pkb(float a, float b) {
    return (__float_as_uint(b) & 0xFFFF0000u) | (__float_as_uint(a) >> 16);
}

// ---------------- pack: antecedents -> entry-index word ---------------------
// w & 0xFFFF = entry index into quad table 0 (0..4095)
// w >> 16    = entry index into quad table 1 (4096..8191, base pre-added)
__global__ __launch_bounds__(256) void pack_kernel(const int* __restrict__ ant,
                                                   unsigned* __restrict__ g_off,
                                                   int R) {
    int r = blockIdx.x * 256 + threadIdx.x;
    if (r < R) {
        const int4* a = reinterpret_cast<const int4*>(ant) + (size_t)r * 2;
        int4 lo = a[0], hi = a[1];
        int v[8] = {lo.x, lo.y, lo.z, lo.w, hi.x, hi.y, hi.z, hi.w};
        unsigned code = 0u;
        #pragma unroll
        for (int i = 0; i < 8; ++i) {
            int c = v[i];
            c = (c < 0) ? 7 : (c > MM - 1 ? MM - 1 : c);   // -1 -> wildcard slot 7
            code |= (unsigned)c << (3 * i);
        }
        g_off[r] = (code & 4095u) | (((code >> 12) + 4096u) << 16);
    }
}

// =================== fused kernel: 8 rows/block, scan + select ==============
// R14 + forced-MLP phase 3: inline-asm ds_read_b128 with "=v" outputs (the
// compiler CANNOT sink opaque asm defs to uses -- R7/R8/R11's C++ ILP was all
// re-sunk, VGPR=32) -> 16 outstanding LDS reads per 8-rule batch, one
// lgkmcnt(0) per batch instead of per rule. sched_barrier(0) walls per guide
// rule #18. Plus phase-2 A-side hoist (136->88 LDS ops/thread) and defuzz
// constants computed under phase 4 (waves 8-15 idle there).
__global__ __launch_bounds__(THREADS, 4) void anfis_fused8(
    const float* __restrict__ x,
    const unsigned* __restrict__ stream_off,
    const int* __restrict__ consequents,
    const float* __restrict__ in_centers,   // [D][M]
    const float* __restrict__ in_widths,    // [D][M]
    const float* __restrict__ out_centers,  // [MO]
    const float* __restrict__ out_widths,   // [MO]
    float* __restrict__ out)
{
    __shared__ uint4 quads[8192];        // 128 KB; aliased after phase 3:
                                         //   bytes [0,16K):  ushort wl[8192]
                                         //   bytes [16K,24K): float cvals[8][256]
                                         //   bytes [24K,32K): int   cidx[8][256]
    __shared__ float mu[ROWS][64];       // 2 KB
    __shared__ float pairs[ROWS][256];   // 8 KB exact f32 pair products
    __shared__ uint4 smaxpk[THREADS];    // 16 KB packed thread maxes
    __shared__ float s0s[MOO], s1s[MOO];
    __shared__ float sT[ROWS];
    __shared__ int   scnt[ROWS];
    __shared__ int   wlcnt;
    __shared__ float wv[ROWS][8];
    __shared__ int   wc[ROWS][8];

    const int tid = threadIdx.x;
    const int b0  = blockIdx.x * ROWS;

    unsigned short* wl = (unsigned short*)quads;          // 16 KB
    float* cvals = (float*)(quads + 1024);                // 8 KB  @16K
    int*   cidx  = (int*)(quads + 1536);                  // 8 KB  @24K

    // --- phase 0: membership tables (8 rows) + init ---
    if (tid < 512) {
        int row = tid >> 6, d = (tid >> 3) & 7, c = tid & 7;
        float v = 1.0f;
        if (c < MM) {
            float z = (x[(b0 + row) * DD + d] - in_centers[d * MM + c]) / in_widths[d * MM + c];
            v = expf(-0.5f * z * z);
            v = fminf(v, 1.0f);
            v = fmaxf(v, EPSF);
        }
        mu[row][(d << 3) + c] = v;
    } else if (tid >= 544 && tid < 544 + ROWS) {
        scnt[tid - 544] = 0;
    } else if (tid == 560) {
        wlcnt = 0;
    }
    __syncthreads();

    // --- phase 1: exact pair products (2048 entries, 2/thread) ---
    #pragma unroll
    for (int i = 0; i < 2; ++i) {
        int k = tid + i * THREADS;
        int row = k >> 8, e = k & 255;
        int p = e >> 6, q = e & 63;
        pairs[row][e] = mu[row][(2 * p) * 8 + (q & 7)] * mu[row][(2 * p + 1) * 8 + (q >> 3)];
    }
    __syncthreads();

    // --- phase 2: quad tables, bf16 x 8 rows per 16B entry, A-side hoisted ---
    // k = tid + (h*4+ii)*1024: ia = h*128 + (tid&63) is CONSTANT across ii.
    #pragma unroll
    for (int h = 0; h < 2; ++h) {
        float a8[ROWS];
        const int ia = h * 128 + (tid & 63);
        #pragma unroll
        for (int r = 0; r < ROWS; ++r) a8[r] = pairs[r][ia];
        #pragma unroll
        for (int ii = 0; ii < 4; ++ii) {
            int k = tid + (h * 4 + ii) * THREADS;
            int ib = h * 128 + 64 + ((((tid >> 6) + 16 * ii)) & 63);
            float q0 = a8[0] * pairs[0][ib];
            float q1 = a8[1] * pairs[1][ib];
            float q2 = a8[2] * pairs[2][ib];
            float q3 = a8[3] * pairs[3][ib];
            float q4 = a8[4] * pairs[4][ib];
            float q5 = a8[5] * pairs[5][ib];
            float q6 = a8[6] * pairs[6][ib];
            float q7 = a8[7] * pairs[7][ib];
            quads[k] = make_uint4(pkb(q0, q1), pkb(q2, q3), pkb(q4, q5), pkb(q6, q7));
        }
    }
    __syncthreads();

    // --- phase 3: scan; 8-rule batches of 16 asm ds_read_b128 (forced MLP) ---
    const uint4* pk4 = reinterpret_cast<const uint4*>(stream_off);
    const unsigned qbase = (unsigned)(uintptr_t)&quads[0];
    float m[ROWS];
    #pragma unroll
    for (int r = 0; r < ROWS; ++r) m[r] = -1.0f;
    #pragma unroll
    for (int half = 0; half < 4; ++half) {
        uint4 cA = pk4[(2 * half) * THREADS + tid];
        uint4 cB = pk4[(2 * half + 1) * THREADS + tid];
        unsigned w[8] = {cA.x, cA.y, cA.z, cA.w, cB.x, cB.y, cB.z, cB.w};
        uint32x4 eA[8], eB[8];
        #pragma unroll
        for (int s = 0; s < 8; ++s) {
            unsigned alo = qbase + ((w[s] & 0xFFFFu) << 4);
            unsigned ahi = qbase + ((w[s] >> 16) << 4);
            asm volatile("ds_read_b128 %0, %1" : "=v"(eA[s]) : "v"(alo));
            asm volatile("ds_read_b128 %0, %1" : "=v"(eB[s]) : "v"(ahi));
        }
        __builtin_amdgcn_sched_barrier(0);
        asm volatile("s_waitcnt lgkmcnt(0)" ::: "memory");
        __builtin_amdgcn_sched_barrier(0);
        #pragma unroll
        for (int s = 0; s < 8; ++s) {
            uint32x4 a = eA[s], b = eB[s];
            m[0] = fmaxf(m[0], bl(a[0]) * bl(b[0]));
            m[1] = fmaxf(m[1], bh(a[0]) * bh(b[0]));
            m[2] = fmaxf(m[2], bl(a[1]) * bl(b[1]));
            m[3] = fmaxf(m[3], bh(a[1]) * bh(b[1]));
            m[4] = fmaxf(m[4], bl(a[2]) * bl(b[2]));
            m[5] = fmaxf(m[5], bh(a[2]) * bh(b[2]));
            m[6] = fmaxf(m[6], bl(a[3]) * bl(b[3]));
            m[7] = fmaxf(m[7], bh(a[3]) * bh(b[3]));
        }
    }
    smaxpk[tid] = make_uint4(pkb(m[0], m[1]), pkb(m[2], m[3]),
                             pkb(m[4], m[5]), pkb(m[6], m[7]));
    __syncthreads();          // quads DEAD from here on

    // --- phase 4: waves 0-7 extract thresholds; wave 8 does defuzz consts ---
    if (tid < 512) {
        int row = tid >> 6, lane = tid & 63;
        float mm[16];
        #pragma unroll
        for (int k = 0; k < 16; ++k) {
            uint4 e = smaxpk[lane + 64 * k];
            unsigned word = (row & 4) ? ((row & 2) ? e.w : e.z)
                                      : ((row & 2) ? e.y : e.x);
            mm[k] = (row & 1) ? bh(word) : bl(word);
        }
        float thr = -1.0f;
        #pragma unroll
        for (int round = 0; round < 8; ++round) {
            float lm = mm[0];
            #pragma unroll
            for (int k = 1; k < 16; ++k) lm = fmaxf(lm, mm[k]);
            float wm = lm;
            #pragma unroll
            for (int off = 32; off >= 1; off >>= 1)
                wm = fmaxf(wm, __shfl_xor(wm, off, 64));
            unsigned long long bal = __ballot(lm == wm);
            int first = (int)__ffsll(bal) - 1;
            if (lane == first) {                // remove exactly one instance
                bool done = false;
                #pragma unroll
                for (int k = 0; k < 16; ++k) {
                    bool rm = (!done) && (mm[k] == wm);
                    mm[k] = rm ? -2.0f : mm[k];
                    done = done || rm;
                }
            }
            thr = wm;
        }
        if (lane == 0) sT[row] = thr;
    } else if (tid < 512 + MOO) {
        int mo = tid - 512;
        float oc = out_centers[mo], ow = out_widths[mo];
        float s0 = 0.0f, s1 = 0.0f;
        for (int p = 0; p < NPTS; ++p) {
            float u = (float)p * (1.0f / 99.0f);
            float z = (u - oc) / ow;
            float e = expf(-0.5f * z * z);
            s0 += e;
            s1 += u * e;
        }
        s0s[mo] = s0;
        s1s[mo] = s1;
    }
    __syncthreads();

    // --- phase 5: build compacted worklist from register maxes ---
    {
        #pragma unroll
        for (int row = 0; row < ROWS; ++row) {
            if (m[row] >= THR_SLACK * sT[row]) {
                int pos = atomicAdd(&wlcnt, 1);
                wl[pos] = (unsigned short)((row << 10) | tid);   // max 8192 items
            }
        }
    }
    __syncthreads();

    // --- phase 6: half-wave per item; lane = one of the thread's 32 rules ---
    {
        const int hl = tid & 31;                   // rule slot within item
        const int j = hl >> 2, s = hl & 3;
        const int n = wlcnt;
        for (int i = (tid >> 5); i < n; i += 32) {
            int it  = wl[i];
            int row = it >> 10;
            int t   = it & 1023;
            int flat = (j * THREADS + t) * 4 + s;
            unsigned w = stream_off[flat];
            unsigned lo12 = w & 0xFFFFu;
            unsigned hi12 = (w >> 16) - 4096u;
            const float* P = pairs[row];
            float f = (P[lo12 & 63u] * P[64 + (lo12 >> 6)])
                    * (P[128 + (hi12 & 63u)] * P[192 + (hi12 >> 6)]);
            if (f >= sT[row]) {
                int pos = atomicAdd(&scnt[row], 1);
                if (pos < CAP) {
                    cvals[row * CAP + pos] = f;
                    cidx[row * CAP + pos]  = flat;
                }
            }
        }
    }
    __syncthreads();

    // --- phase 7: exact rank selection per row (val desc, orig idx asc) ---
    if (tid < 512) {
        int row = tid >> 6, lane = tid & 63;
        int n = scnt[row] < CAP ? scnt[row] : CAP;
        for (int c = lane; c < n; c += 64) {
            float v  = cvals[row * CAP + c];
            int   id = cidx[row * CAP + c];
            int rk = 0;
            for (int mI = 0; mI < n; ++mI) {
                float vm = cvals[row * CAP + mI];
                int   im = cidx[row * CAP + mI];
                rk += ((vm > v) || (vm == v && im < id)) ? 1 : 0;
            }
            if (rk < 8) {
                wv[row][rk] = v;
                wc[row][rk] = consequents[id];
            }
        }
    }
    __syncthreads();

    // --- phase 8: defuzzify ---
    if (tid < ROWS) {
        int row = tid;
        float num = 0.0f, den = 0.0f;
        #pragma unroll
        for (int k = 0; k < 8; ++k) {
            num += wv[row][k] * s1s[wc[row][k]];
            den += wv[row][k] * s0s[wc[row][k]];
        }
        out[b0 + row] = num / (den + EPSF);
    }
}

// ---------------- generic fallback (round-1 kernel, inline pack) ------------
__global__ __launch_bounds__(256) void anfis_kernel(
    const float* __restrict__ x,
    const int* __restrict__ ant,
    const int* __restrict__ consequents,
    const float* __restrict__ in_centers,
    const float* __restrict__ in_widths,
    const float* __restrict__ out_centers,
    const float* __restrict__ out_widths,
    float* __restrict__ out,
    int R)
{
    __shared__ float mu[64];
    __shared__ float pairs[256];
    __shared__ float s0s[MOO], s1s[MOO];
    __shared__ float svals[256][9];
    __shared__ int   sidx[256][9];

    const int tid = threadIdx.x;
    const int b   = blockIdx.x;

    if (tid < 64) {
        int d = tid >> 3, c = tid & 7;
        float v = 1.0f;
        if (c < MM) {
            float z = (x[b * DD + d] - in_centers[d * MM + c]) / in_widths[d * MM + c];
            v = expf(-0.5f * z * z);
            v = fminf(v, 1.0f);
            v = fmaxf(v, EPSF);
        }
        mu[tid] = v;
    } else if (tid < 64 + MOO) {
        int mo = tid - 64;
        float oc = out_centers[mo], ow = out_widths[mo];
        float s0 = 0.0f, s1 = 0.0f;
        for (int p = 0; p < NPTS; ++p) {
            float u = (float)p * (1.0f / 99.0f);
            float z = (u - oc) / ow;
            float e = expf(-0.5f * z * z);
            s0 += e;
            s1 += u * e;
        }
        s0s[mo] = s0;
        s1s[mo] = s1;
    }
    __syncthreads();

    {
        int p = tid >> 6, q = tid & 63;
        pairs[tid] = mu[(2 * p) * 8 + (q & 7)] * mu[(2 * p + 1) * 8 + (q >> 3)];
    }
    __syncthreads();

    float vals[8];
    int   idxs[8];
    #pragma unroll
    for (int k = 0; k < 8; ++k) { vals[k] = -1.0f; idxs[k] = 0x7fffffff; }

    for (int r = tid; r < R; r += 256) {
        const int4* a = reinterpret_cast<const int4*>(ant) + (size_t)r * 2;
        int4 lo = a[0], hi = a[1];
        int v[8] = {lo.x, lo.y, lo.z, lo.w, hi.x, hi.y, hi.z, hi.w};
        unsigned code = 0u;
        #pragma unroll
        for (int i = 0; i < 8; ++i) {
            int c = v[i];
            c = (c < 0) ? 7 : (c > MM - 1 ? MM - 1 : c);
            code |= (unsigned)c << (3 * i);
        }
        float f = pairs[code & 63]
                * pairs[64  + ((code >> 6)  & 63)]
                * pairs[128 + ((code >> 12) & 63)]
                * pairs[192 + ((code >> 18) & 63)];
        if (f > vals[7]) {
            float nv = f; int ni = r;
            #pragma unroll
            for (int k = 0; k < 8; ++k) {
                bool take = nv > vals[k];
                float cv = vals[k]; int ci = idxs[k];
                vals[k] = take ? nv : cv;
                idxs[k] = take ? ni : ci;
                nv = take ? cv : nv;
                ni = take ? ci : ni;
            }
        }
    }

    #pragma unroll
    for (int k = 0; k < 8; ++k) { svals[tid][k] = vals[k]; sidx[tid][k] = idxs[k]; }

    for (int off = 128; off >= 1; off >>= 1) {
        __syncthreads();
        if (tid < off) {
            float ov[8]; int oi[8];
            int pa = 0, pb = 0;
            #pragma unroll
            for (int k = 0; k < 8; ++k) {
                float va = svals[tid][pa];        int ia = sidx[tid][pa];
                float vb = svals[tid + off][pb];  int ib = sidx[tid + off][pb];
                bool ta = (va > vb) || ((va == vb) && (ia < ib));
                ov[k] = ta ? va : vb;
                oi[k] = ta ? ia : ib;
                pa += ta ? 1 : 0;
                pb += ta ? 0 : 1;
            }
            #pragma unroll
            for (int k = 0; k < 8; ++k) { svals[tid][k] = ov[k]; sidx[tid][k] = oi[k]; }
        }
    }
    __syncthreads();

    if (tid == 0) {
        float num = 0.0f, den = 0.0f;
        #pragma unroll
        for (int k = 0; k < 8; ++k) {
            float v = svals[0][k];
            int   c = consequents[sidx[0][k]];
            num += v * s1s[c];
            den += v * s0s[c];
        }
        out[b] = num / (den + EPSF);
    }
}

extern "C" void kernel_launch(void* const* d_in, const int* in_sizes, int n_in,
                              void* d_out, int out_size, void* d_ws, size_t ws_size,
                              hipStream_t stream) {
    const float* x      = (const float*)d_in[0];
    const int*   ant    = (const int*)d_in[1];
    const int*   cons   = (const int*)d_in[2];
    const float* in_c   = (const float*)d_in[3];
    const float* in_w   = (const float*)d_in[4];
    const float* out_c  = (const float*)d_in[5];
    const float* out_w  = (const float*)d_in[6];
    float*       out    = (float*)d_out;

    const int B = in_sizes[0] / DD;
    const int R = in_sizes[1] / DD;

    const bool shape_ok = (R == THREADS * 4 * ITERS) && (B % ROWS == 0);
    const size_t need = (size_t)R * 4;    // packed words only

    if (shape_ok && d_ws && ws_size >= need) {
        unsigned* g_off = (unsigned*)d_ws;
        pack_kernel<<<(R + 255) / 256, 256, 0, stream>>>(ant, g_off, R);
        anfis_fused8<<<B / ROWS, THREADS, 0, stream>>>(x, g_off, cons, in_c, in_w,
                                                       out_c, out_w, out);
    } else {
        anfis_kernel<<<B, 256, 0, stream>>>(x, ant, cons, in_c, in_w,
                                            out_c, out_w, out, R);
    }
}